// Round 1
// baseline (1357.633 us; speedup 1.0000x reference)
//
// TrigonometryUpdate — MI355X round 1: full-structure bf16 MFMA implementation.
// Phases: LN -> proj(gate/lin/g, +efeat rows) -> scatter(fp32 atomics) ->
//         transpose->bf16 ch-first -> fused dual einsum -> LN_C + las + g-gate.
#include <hip/hip_runtime.h>
#include <stdint.h>

#define NN 512
#define EE 256
#define CC 128
#define NEDGE 16384
#define RR (NN*NN)            // 262144 positions
#define RT3 (RR + 2*NEDGE)    // LN'd rows: z + efeat1 + efeat2

using bf16x8 = __attribute__((ext_vector_type(8))) short;
using f32x4  = __attribute__((ext_vector_type(4))) float;

__device__ __forceinline__ unsigned short f2bf(float f) {
  union { float f; unsigned u; } v; v.f = f;
  unsigned r = v.u + 0x7FFFu + ((v.u >> 16) & 1u);
  return (unsigned short)(r >> 16);
}
__device__ __forceinline__ float bf2f(unsigned short h) {
  union { unsigned u; float f; } v; v.u = ((unsigned)h) << 16;
  return v.f;
}
__device__ __forceinline__ float sigm(float x) { return 1.f / (1.f + __expf(-x)); }

// ---------------- LN over E for z, efeat1, efeat2 -> zl bf16 [RT3][256] ------
__global__ __launch_bounds__(256) void k_ln(
    const float* __restrict__ z, const float* __restrict__ e1,
    const float* __restrict__ e2, const float* __restrict__ lnw,
    const float* __restrict__ lnb, unsigned short* __restrict__ zl) {
  int row = blockIdx.x * 4 + (threadIdx.x >> 6);
  int lane = threadIdx.x & 63;
  const float* src;
  if (row < RR)            src = z  + (size_t)row * EE;
  else if (row < RR+NEDGE) src = e1 + (size_t)(row - RR) * EE;
  else                     src = e2 + (size_t)(row - RR - NEDGE) * EE;
  float4 v = ((const float4*)src)[lane];
  float s = v.x + v.y + v.z + v.w;
  float q = v.x*v.x + v.y*v.y + v.z*v.z + v.w*v.w;
  #pragma unroll
  for (int o = 32; o > 0; o >>= 1) { s += __shfl_xor(s, o); q += __shfl_xor(q, o); }
  float m = s * (1.f/EE);
  float rstd = rsqrtf(q*(1.f/EE) - m*m + 1e-5f);
  float4 wv = ((const float4*)lnw)[lane];
  float4 bv = ((const float4*)lnb)[lane];
  ushort4 o4;
  o4.x = f2bf((v.x - m)*rstd*wv.x + bv.x);
  o4.y = f2bf((v.y - m)*rstd*wv.y + bv.y);
  o4.z = f2bf((v.z - m)*rstd*wv.z + bv.z);
  o4.w = f2bf((v.w - m)*rstd*wv.w + bv.w);
  ((ushort4*)(zl + (size_t)row * EE))[lane] = o4;
}

// ---------------- weights fp32 -> bf16 packs --------------------------------
// Wcol = [gl1;l1] (256x256), Wrow = [gl2;l2;eg] (512x256), Wlas = las (256x128)
__global__ __launch_bounds__(256) void k_wconv(
    const float* __restrict__ gl1, const float* __restrict__ l1,
    const float* __restrict__ gl2, const float* __restrict__ l2,
    const float* __restrict__ eg,  const float* __restrict__ las,
    unsigned short* __restrict__ Wcol, unsigned short* __restrict__ Wrow,
    unsigned short* __restrict__ Wlas) {
  int t = blockIdx.x * 256 + threadIdx.x;   // 229376 total
  if (t < 65536) {
    Wcol[t] = f2bf(t < 32768 ? gl1[t] : l1[t - 32768]);
  } else if (t < 196608) {
    int u = t - 65536;
    float v = (u < 32768) ? gl2[u] : (u < 65536) ? l2[u - 32768] : eg[u - 65536];
    Wrow[u] = f2bf(v);
  } else {
    int u = t - 196608;
    Wlas[u] = f2bf(las[u]);
  }
}

// ---------------- paired gate projection (sigmoid(xGt+gb)*(xLt+lb)) ---------
// mode 0: column-major z tiles -> ab1t[c][pos2*512+pos1]; efeat1 -> P1f scatter
// mode 1: row-major   z tiles -> ab2c[c][pos1*512+pos2]; efeat2 -> P2f scatter
__global__ __launch_bounds__(256) void k_proj_gate(
    const unsigned short* __restrict__ zl, const unsigned short* __restrict__ W,
    const float* __restrict__ gb, const float* __restrict__ lb,
    unsigned short* __restrict__ abOut, float* __restrict__ Pf,
    const int* __restrict__ edges, int mode) {
  __shared__ __attribute__((aligned(16))) short As[128*32];
  __shared__ __attribute__((aligned(16))) short Bg[128*32];
  __shared__ __attribute__((aligned(16))) short Bl[128*32];
  const int t = threadIdx.x, w = t >> 6, lane = t & 63;
  const int mt = blockIdx.x;
  const bool isE = (mt >= RR/128);
  size_t abase; int astride;
  if (!isE) {
    if (mode == 0) { int rt0 = mt*128; abase = (size_t)(rt0 & 511)*512 + (rt0 >> 9); astride = 512; }
    else           { abase = (size_t)mt*128; astride = 1; }
  } else {
    abase = (size_t)RR + (mode ? NEDGE : 0) + (mt*128 - RR); astride = 1;
  }
  const f32x4 z4 = {0.f, 0.f, 0.f, 0.f};
  f32x4 ag[4][4], al[4][4];
  #pragma unroll
  for (int a = 0; a < 4; ++a)
    #pragma unroll
    for (int b = 0; b < 4; ++b) { ag[a][b] = z4; al[a][b] = z4; }
  const int wr = (w >> 1)*64, wc = (w & 1)*64;
  #pragma unroll 1
  for (int kk = 0; kk < 8; ++kk) {
    const int k0 = kk * 32;
    __syncthreads();
    #pragma unroll
    for (int s2 = 0; s2 < 2; ++s2) {
      int sidx = t + s2*256, row = sidx >> 2, seg = sidx & 3;
      int lo = row*32 + seg*8;
      *(uint4*)&As[lo] = *(const uint4*)(zl + (abase + (size_t)row*astride)*EE + k0 + seg*8);
      const unsigned short* wp = W + (size_t)row*EE + k0 + seg*8;
      *(uint4*)&Bg[lo] = *(const uint4*)wp;
      *(uint4*)&Bl[lo] = *(const uint4*)(wp + 128*EE);
    }
    __syncthreads();
    bf16x8 af[4], bgf[4], blf[4];
    #pragma unroll
    for (int f = 0; f < 4; ++f) {
      af[f]  = *(const bf16x8*)&As[(wr + f*16 + (lane & 15))*32 + (lane >> 4)*8];
      bgf[f] = *(const bf16x8*)&Bg[(wc + f*16 + (lane & 15))*32 + (lane >> 4)*8];
      blf[f] = *(const bf16x8*)&Bl[(wc + f*16 + (lane & 15))*32 + (lane >> 4)*8];
    }
    #pragma unroll
    for (int fm = 0; fm < 4; ++fm)
      #pragma unroll
      for (int fn = 0; fn < 4; ++fn) {
        ag[fm][fn] = __builtin_amdgcn_mfma_f32_16x16x32_bf16(af[fm], bgf[fn], ag[fm][fn], 0, 0, 0);
        al[fm][fn] = __builtin_amdgcn_mfma_f32_16x16x32_bf16(af[fm], blf[fn], al[fm][fn], 0, 0, 0);
      }
  }
  const int quad = lane >> 4, lc = lane & 15;
  #pragma unroll
  for (int fm = 0; fm < 4; ++fm)
    #pragma unroll
    for (int fn = 0; fn < 4; ++fn) {
      int c = wc + fn*16 + lc;
      float bgv = gb[c], blv = lb[c];
      float v0 = sigm(ag[fm][fn][0] + bgv) * (al[fm][fn][0] + blv);
      float v1 = sigm(ag[fm][fn][1] + bgv) * (al[fm][fn][1] + blv);
      float v2 = sigm(ag[fm][fn][2] + bgv) * (al[fm][fn][2] + blv);
      float v3 = sigm(ag[fm][fn][3] + bgv) * (al[fm][fn][3] + blv);
      int rl = wr + fm*16 + quad*4;
      if (!isE) {
        size_t rt = (size_t)mt*128 + rl;
        ushort4 o; o.x = f2bf(v0); o.y = f2bf(v1); o.z = f2bf(v2); o.w = f2bf(v3);
        *(ushort4*)&abOut[(size_t)c*RR + rt] = o;
      } else {
        int e0 = mt*128 - RR + rl;
        float vv[4] = {v0, v1, v2, v3};
        #pragma unroll
        for (int rg = 0; rg < 4; ++rg) {
          int e = e0 + rg;
          int i0 = edges[e], i1 = edges[NEDGE + e];
          atomicAdd(&Pf[((size_t)i0*NN + i1)*CC + c], vv[rg]);
        }
      }
    }
}

// ---------------- g = sigmoid(zl @ eg^T + eg_b), z rows only ----------------
__global__ __launch_bounds__(256) void k_proj_g(
    const unsigned short* __restrict__ zl, const unsigned short* __restrict__ Weg,
    const float* __restrict__ egb, unsigned short* __restrict__ gOut) {
  __shared__ __attribute__((aligned(16))) short As[128*32];
  __shared__ __attribute__((aligned(16))) short Bs[128*32];
  const int t = threadIdx.x, w = t >> 6, lane = t & 63;
  const int mt = blockIdx.x, half = blockIdx.y;
  const size_t abase = (size_t)mt * 128;
  const unsigned short* Wb = Weg + (size_t)half * 128 * EE;
  const f32x4 z4 = {0.f, 0.f, 0.f, 0.f};
  f32x4 acc[4][4];
  #pragma unroll
  for (int a = 0; a < 4; ++a)
    #pragma unroll
    for (int b = 0; b < 4; ++b) acc[a][b] = z4;
  const int wr = (w >> 1)*64, wc = (w & 1)*64;
  #pragma unroll 1
  for (int kk = 0; kk < 8; ++kk) {
    const int k0 = kk * 32;
    __syncthreads();
    #pragma unroll
    for (int s2 = 0; s2 < 2; ++s2) {
      int sidx = t + s2*256, row = sidx >> 2, seg = sidx & 3;
      int lo = row*32 + seg*8;
      *(uint4*)&As[lo] = *(const uint4*)(zl + (abase + row)*EE + k0 + seg*8);
      *(uint4*)&Bs[lo] = *(const uint4*)(Wb + (size_t)row*EE + k0 + seg*8);
    }
    __syncthreads();
    bf16x8 af[4], bf_[4];
    #pragma unroll
    for (int f = 0; f < 4; ++f) {
      af[f]  = *(const bf16x8*)&As[(wr + f*16 + (lane & 15))*32 + (lane >> 4)*8];
      bf_[f] = *(const bf16x8*)&Bs[(wc + f*16 + (lane & 15))*32 + (lane >> 4)*8];
    }
    #pragma unroll
    for (int fm = 0; fm < 4; ++fm)
      #pragma unroll
      for (int fn = 0; fn < 4; ++fn)
        acc[fm][fn] = __builtin_amdgcn_mfma_f32_16x16x32_bf16(af[fm], bf_[fn], acc[fm][fn], 0, 0, 0);
  }
  const int quad = lane >> 4, lc = lane & 15;
  #pragma unroll
  for (int fm = 0; fm < 4; ++fm)
    #pragma unroll
    for (int fn = 0; fn < 4; ++fn) {
      int e = half*128 + wc + fn*16 + lc;
      float bv = egb[e];
      size_t r0 = (size_t)mt*128 + wr + fm*16 + quad*4;
      #pragma unroll
      for (int rg = 0; rg < 4; ++rg)
        gOut[(r0 + rg)*EE + e] = f2bf(sigm(acc[fm][fn][rg] + bv));
    }
}

// ---------------- P fp32 [pos][c] -> bf16 channel-first [c][pos] ------------
__global__ __launch_bounds__(256) void k_pcvt(
    const float* __restrict__ P1f, const float* __restrict__ P2f,
    unsigned short* __restrict__ P1c, unsigned short* __restrict__ P2c) {
  const float* src = blockIdx.y ? P2f : P1f;
  unsigned short* dst = blockIdx.y ? P2c : P1c;
  __shared__ float Ls[128*65];   // [c][p], pad 65
  const int t = threadIdx.x;
  const size_t pos0 = (size_t)blockIdx.x * 64;
  #pragma unroll
  for (int it = 0; it < 8; ++it) {
    int fi = t + it*256;                 // 2048 float4s
    int p = fi >> 5, cq = fi & 31;
    float4 v = ((const float4*)(src + (pos0 + p)*CC))[cq];
    Ls[(cq*4+0)*65 + p] = v.x; Ls[(cq*4+1)*65 + p] = v.y;
    Ls[(cq*4+2)*65 + p] = v.z; Ls[(cq*4+3)*65 + p] = v.w;
  }
  __syncthreads();
  #pragma unroll
  for (int it = 0; it < 8; ++it) {
    int oi = t + it*256;                 // 2048 ushort4s
    int c = oi >> 4, pq = oi & 15;
    ushort4 o;
    o.x = f2bf(Ls[c*65 + pq*4 + 0]); o.y = f2bf(Ls[c*65 + pq*4 + 1]);
    o.z = f2bf(Ls[c*65 + pq*4 + 2]); o.w = f2bf(Ls[c*65 + pq*4 + 3]);
    *(ushort4*)&dst[(size_t)c*RR + pos0 + pq*4] = o;
  }
}

// ---------------- fused dual einsum: S[c][i*512+j] = P1@ab1 + ab2@P2^T ------
__global__ __launch_bounds__(256) void k_einsum(
    const unsigned short* __restrict__ P1c, const unsigned short* __restrict__ ab1t,
    const unsigned short* __restrict__ ab2c, const unsigned short* __restrict__ P2c,
    float* __restrict__ Sf) {
  __shared__ __attribute__((aligned(16))) short A1s[128*32];
  __shared__ __attribute__((aligned(16))) short B1s[128*32];
  __shared__ __attribute__((aligned(16))) short A2s[128*32];
  __shared__ __attribute__((aligned(16))) short B2s[128*32];
  const int t = threadIdx.x, w = t >> 6, lane = t & 63;
  const int ch = blockIdx.y, mt = blockIdx.x & 3, nt = blockIdx.x >> 2;
  const size_t cb = (size_t)ch * RR;
  const unsigned short* A1g = P1c  + cb + (size_t)mt*128*512;
  const unsigned short* B1g = ab1t + cb + (size_t)nt*128*512;
  const unsigned short* A2g = ab2c + cb + (size_t)mt*128*512;
  const unsigned short* B2g = P2c  + cb + (size_t)nt*128*512;
  const f32x4 z4 = {0.f, 0.f, 0.f, 0.f};
  f32x4 acc[4][4];
  #pragma unroll
  for (int a = 0; a < 4; ++a)
    #pragma unroll
    for (int b = 0; b < 4; ++b) acc[a][b] = z4;
  const int wr = (w >> 1)*64, wc = (w & 1)*64;
  #pragma unroll 1
  for (int kk = 0; kk < 16; ++kk) {
    const int k0 = kk * 32;
    __syncthreads();
    #pragma unroll
    for (int s2 = 0; s2 < 2; ++s2) {
      int sidx = t + s2*256, row = sidx >> 2, seg = sidx & 3;
      int go = row*512 + k0 + seg*8;
      int lo = row*32 + seg*8;
      *(uint4*)&A1s[lo] = *(const uint4*)(A1g + go);
      *(uint4*)&B1s[lo] = *(const uint4*)(B1g + go);
      *(uint4*)&A2s[lo] = *(const uint4*)(A2g + go);
      *(uint4*)&B2s[lo] = *(const uint4*)(B2g + go);
    }
    __syncthreads();
    bf16x8 a1[4], b1[4], a2[4], b2[4];
    #pragma unroll
    for (int f = 0; f < 4; ++f) {
      int ro = (wr + f*16 + (lane & 15))*32 + (lane >> 4)*8;
      int co = (wc + f*16 + (lane & 15))*32 + (lane >> 4)*8;
      a1[f] = *(const bf16x8*)&A1s[ro];
      a2[f] = *(const bf16x8*)&A2s[ro];
      b1[f] = *(const bf16x8*)&B1s[co];
      b2[f] = *(const bf16x8*)&B2s[co];
    }
    #pragma unroll
    for (int fm = 0; fm < 4; ++fm)
      #pragma unroll
      for (int fn = 0; fn < 4; ++fn) {
        acc[fm][fn] = __builtin_amdgcn_mfma_f32_16x16x32_bf16(a1[fm], b1[fn], acc[fm][fn], 0, 0, 0);
        acc[fm][fn] = __builtin_amdgcn_mfma_f32_16x16x32_bf16(a2[fm], b2[fn], acc[fm][fn], 0, 0, 0);
      }
  }
  const int quad = lane >> 4, lc = lane & 15;
  #pragma unroll
  for (int fm = 0; fm < 4; ++fm)
    #pragma unroll
    for (int fn = 0; fn < 4; ++fn) {
      int j = nt*128 + wc + fn*16 + lc;
      int ib = mt*128 + wr + fm*16 + quad*4;
      #pragma unroll
      for (int rg = 0; rg < 4; ++rg)
        Sf[cb + (size_t)(ib + rg)*NN + j] = acc[fm][fn][rg];
    }
}

// ---------------- out = g * (LN_C(S) @ las^T + las_b) -----------------------
__global__ __launch_bounds__(256) void k_out(
    const float* __restrict__ Sf, const unsigned short* __restrict__ g,
    const unsigned short* __restrict__ Wlas, const float* __restrict__ lasb,
    const float* __restrict__ lncw, const float* __restrict__ lncb,
    float* __restrict__ out) {
  __shared__ float Sls[64*129];                          // [r][c] pad 129
  __shared__ __attribute__((aligned(16))) short Als[64*128];  // normalized bf16
  const int t = threadIdx.x, w = t >> 6, lane = t & 63;
  const size_t r0 = (size_t)blockIdx.x * 64;
  #pragma unroll
  for (int it = 0; it < 8; ++it) {
    int fi = t + it*256;                 // 2048 float4s: [c][r-quad]
    int c = fi >> 4, rq = fi & 15;
    float4 v = ((const float4*)(Sf + (size_t)c*RR + r0))[rq];
    Sls[(rq*4+0)*129 + c] = v.x; Sls[(rq*4+1)*129 + c] = v.y;
    Sls[(rq*4+2)*129 + c] = v.z; Sls[(rq*4+3)*129 + c] = v.w;
  }
  __syncthreads();
  #pragma unroll 1
  for (int i = 0; i < 16; ++i) {
    int rr = w*16 + i;
    float x1 = Sls[rr*129 + lane], x2 = Sls[rr*129 + 64 + lane];
    float s = x1 + x2, q = x1*x1 + x2*x2;
    #pragma unroll
    for (int o = 32; o > 0; o >>= 1) { s += __shfl_xor(s, o); q += __shfl_xor(q, o); }
    float m = s * (1.f/CC);
    float rstd = rsqrtf(q*(1.f/CC) - m*m + 1e-5f);
    int c1 = lane, c2 = lane + 64;
    Als[rr*128 + c1] = (short)f2bf((x1 - m)*rstd*lncw[c1] + lncb[c1]);
    Als[rr*128 + c2] = (short)f2bf((x2 - m)*rstd*lncw[c2] + lncb[c2]);
  }
  __syncthreads();
  const f32x4 z4 = {0.f, 0.f, 0.f, 0.f};
  f32x4 acc[4][4];
  #pragma unroll
  for (int a = 0; a < 4; ++a)
    #pragma unroll
    for (int b = 0; b < 4; ++b) acc[a][b] = z4;
  const int quad = lane >> 4, lc = lane & 15;
  #pragma unroll
  for (int kk = 0; kk < 4; ++kk) {
    int k0 = kk * 32;
    bf16x8 a[4], b[4];
    #pragma unroll
    for (int f = 0; f < 4; ++f) {
      a[f] = *(const bf16x8*)&Als[(f*16 + lc)*128 + k0 + quad*8];
      int e = w*64 + f*16 + lc;
      b[f] = *(const bf16x8*)&Wlas[(size_t)e*CC + k0 + quad*8];
    }
    #pragma unroll
    for (int fm = 0; fm < 4; ++fm)
      #pragma unroll
      for (int fn = 0; fn < 4; ++fn)
        acc[fm][fn] = __builtin_amdgcn_mfma_f32_16x16x32_bf16(a[fm], b[fn], acc[fm][fn], 0, 0, 0);
  }
  #pragma unroll
  for (int fm = 0; fm < 4; ++fm)
    #pragma unroll
    for (int fn = 0; fn < 4; ++fn) {
      int e = w*64 + fn*16 + lc;
      float lbv = lasb[e];
      #pragma unroll
      for (int rg = 0; rg < 4; ++rg) {
        size_t r = r0 + fm*16 + quad*4 + rg;
        float gv = bf2f(g[r*EE + e]);
        out[r*EE + e] = gv * (acc[fm][fn][rg] + lbv);
      }
    }
}

// ---------------------------------------------------------------------------
extern "C" void kernel_launch(void* const* d_in, const int* in_sizes, int n_in,
                              void* d_out, int out_size, void* d_ws, size_t ws_size,
                              hipStream_t stream) {
  const float* z    = (const float*)d_in[0];
  const float* ef1  = (const float*)d_in[1];
  const float* ef2  = (const float*)d_in[2];
  const float* lnw  = (const float*)d_in[3];
  const float* lnb  = (const float*)d_in[4];
  const float* lncw = (const float*)d_in[5];
  const float* lncb = (const float*)d_in[6];
  const float* gl1w = (const float*)d_in[7];
  const float* gl1b = (const float*)d_in[8];
  const float* gl2w = (const float*)d_in[9];
  const float* gl2b = (const float*)d_in[10];
  const float* l1w  = (const float*)d_in[11];
  const float* l1b  = (const float*)d_in[12];
  const float* l2w  = (const float*)d_in[13];
  const float* l2b  = (const float*)d_in[14];
  const float* egw  = (const float*)d_in[15];
  const float* egb  = (const float*)d_in[16];
  const float* lasw = (const float*)d_in[17];
  const float* lasb = (const float*)d_in[18];
  const int* edges1 = (const int*)d_in[19];
  const int* edges2 = (const int*)d_in[20];
  float* out = (float*)d_out;

  char* ws = (char*)d_ws;
  // layout (aliased across phases):
  // [0, 151.0M): zl bf16 [RT3][256];  reused later: P1c (67.1M) + P2c (67.1M)
  unsigned short* zl   = (unsigned short*)(ws);
  unsigned short* P1c  = (unsigned short*)(ws);
  unsigned short* P2c  = (unsigned short*)(ws + 67108864);
  unsigned short* ab1t = (unsigned short*)(ws + 150994944);   // 67.1M bf16 [c][j*512+i]
  unsigned short* ab2c = (unsigned short*)(ws + 218103808);   // 67.1M bf16 [c][i*512+k]
  unsigned short* gbuf = (unsigned short*)(ws + 285212672);   // 134.2M bf16 [r][256]
  float* P1f = (float*)(ws + 419430400);                      // 134.2M fp32 [pos][c]
  float* Sf  = (float*)(ws + 419430400);                      // alias after P1f dead
  float* P2f = (float*)(ws + 553648128);                      // 134.2M fp32 [pos][c]
  unsigned short* Wcol = (unsigned short*)(ws + 687865856);
  unsigned short* Wrow = (unsigned short*)(ws + 687996928);
  unsigned short* Wlas = (unsigned short*)(ws + 688259072);
  // total = 688,324,608 bytes

  hipMemsetAsync(P1f, 0, (size_t)RR*CC*4, stream);
  hipMemsetAsync(P2f, 0, (size_t)RR*CC*4, stream);
  k_wconv<<<896, 256, 0, stream>>>(gl1w, l1w, gl2w, l2w, egw, lasw, Wcol, Wrow, Wlas);
  k_ln<<<RT3/4, 256, 0, stream>>>(z, ef1, ef2, lnw, lnb, zl);
  k_proj_gate<<<2176, 256, 0, stream>>>(zl, Wcol, gl1b, l1b, ab1t, P1f, edges1, 0);
  k_proj_gate<<<2176, 256, 0, stream>>>(zl, Wrow, gl2b, l2b, ab2c, P2f, edges2, 1);
  k_proj_g<<<dim3(2048, 2), 256, 0, stream>>>(zl, Wrow + 256*EE, egb, gbuf);
  k_pcvt<<<dim3(4096, 2), 256, 0, stream>>>(P1f, P2f, P1c, P2c);
  k_einsum<<<dim3(16, 128), 256, 0, stream>>>(P1c, ab1t, ab2c, P2c, Sf);
  k_out<<<4096, 256, 0, stream>>>(Sf, gbuf, Wlas, lasb, lncw, lncb, out);
}